// Round 12
// baseline (1192.770 us; speedup 1.0000x reference)
//
#include <hip/hip_runtime.h>
#include <hip/hip_bf16.h>

// Problem constants: B=128, N=1024, E=16384, ENTITY=100000, EMB=100, HID=100

typedef unsigned int u32;
typedef float f2 __attribute__((ext_vector_type(2)));

__device__ __forceinline__ float bflo(u32 u) {
    union { u32 i; float f; } v; v.i = u << 16; return v.f;
}
__device__ __forceinline__ float bfhi(u32 u) {
    union { u32 i; float f; } v; v.i = u & 0xffff0000u; return v.f;
}
__device__ __forceinline__ u32 f2bf1(float f) {
    union { float f; u32 u; } v; v.f = f;
    return (v.u + 0x7fffu + ((v.u >> 16) & 1u)) >> 16;   // RNE
}
__device__ __forceinline__ u32 packbf(float a, float b) {
    return f2bf1(a) | (f2bf1(b) << 16);
}
__device__ __forceinline__ float sigm(float x) { return 1.f / (1.f + __expf(-x)); }
__device__ __forceinline__ float tanh_fast(float x) {
    float e = __expf(2.f * x);
    return 1.f - 2.f / (e + 1.f);
}

// ---------------------------------------------------------------------------
// Kernel 1: embedding gather + GCN matmul.  support[n][h] (bf16 packed u32)
// ---------------------------------------------------------------------------
__global__ __launch_bounds__(256, 2)
void gcn_kernel(const int* __restrict__ nb, const float* __restrict__ emb,
                const float* __restrict__ w, u32* __restrict__ support)
{
    __shared__ float wl[10000];
    for (int i = threadIdx.x; i < 10000; i += 256) wl[i] = w[i];
    __syncthreads();

    const int n = blockIdx.x * 256 + threadIdx.x;
    const long long row = nb[n];
    const float4* __restrict__ xr = (const float4*)(emb + row * 100);

    float acc[100];
#pragma unroll
    for (int h = 0; h < 100; ++h) acc[h] = 0.f;

    for (int kk = 0; kk < 25; ++kk) {
        const float4 xv = xr[kk];
        const float xs[4] = { xv.x, xv.y, xv.z, xv.w };
#pragma unroll
        for (int q = 0; q < 4; ++q) {
            const float* wrow = &wl[(kk * 4 + q) * 100];
            const float xq = xs[q];
#pragma unroll
            for (int h4 = 0; h4 < 25; ++h4) {
                const float4 w4 = *(const float4*)(wrow + h4 * 4);
                acc[h4*4+0] = fmaf(xq, w4.x, acc[h4*4+0]);
                acc[h4*4+1] = fmaf(xq, w4.y, acc[h4*4+1]);
                acc[h4*4+2] = fmaf(xq, w4.z, acc[h4*4+2]);
                acc[h4*4+3] = fmaf(xq, w4.w, acc[h4*4+3]);
            }
        }
    }

    u32* __restrict__ o = support + (size_t)n * 50;
#pragma unroll
    for (int i = 0; i < 50; ++i) o[i] = packbf(acc[2*i], acc[2*i+1]);
}

// ---------------------------------------------------------------------------
// Kernel 2a: per-sample counting-sort into CSR order.
// ---------------------------------------------------------------------------
__global__ __launch_bounds__(256, 2)
void csr_build(const int* __restrict__ arow, const int* __restrict__ acol,
               const float* __restrict__ aval,
               int* __restrict__ offs, int2* __restrict__ csr)
{
    __shared__ int cnt[1024];
    __shared__ int part[256];
    __shared__ int offl[1024];

    const int b   = blockIdx.x;
    const int tid = threadIdx.x;
    const int*   rw = arow + b * 16384;
    const int*   cl = acol + b * 16384;
    const float* vl = aval + b * 16384;

    for (int i = tid; i < 1024; i += 256) cnt[i] = 0;
    __syncthreads();
    for (int e = tid; e < 16384; e += 256) atomicAdd(&cnt[rw[e]], 1);
    __syncthreads();

    int c[4]; int s = 0;
#pragma unroll
    for (int q = 0; q < 4; ++q) { c[q] = cnt[tid * 4 + q]; s += c[q]; }
    part[tid] = s;
    __syncthreads();
    for (int off = 1; off < 256; off <<= 1) {
        int v = (tid >= off) ? part[tid - off] : 0;
        __syncthreads();
        part[tid] += v;
        __syncthreads();
    }
    int run = part[tid] - s;
#pragma unroll
    for (int q = 0; q < 4; ++q) { offl[tid * 4 + q] = run; run += c[q]; }
    __syncthreads();

    for (int i = tid; i < 1024; i += 256) offs[b * 1025 + i] = offl[i];
    if (tid == 0) offs[b * 1025 + 1024] = 16384;

    int2* cs = csr + (size_t)b * 16384;
    for (int e = tid; e < 16384; e += 256) {
        const int r   = rw[e];
        const int pos = atomicAdd(&offl[r], 1);
        int2 cv; cv.x = cl[e]; cv.y = __float_as_int(vl[e]);
        cs[pos] = cv;
    }
}

// ---------------------------------------------------------------------------
// Kernel 2b: atomic-free CSR aggregate.  50 lanes/row.
// ---------------------------------------------------------------------------
__global__ __launch_bounds__(256, 4)
void spmm_agg(const int* __restrict__ offs, const int2* __restrict__ csr,
              const u32* __restrict__ support,
              const float* __restrict__ gcn_b, u32* __restrict__ seq)
{
    const int b    = blockIdx.y;
    const int lr   = threadIdx.x / 50;
    const int lane = threadIdx.x % 50;
    const int r    = blockIdx.x * 5 + lr;
    if (lr >= 5 || r >= 1024) return;

    const int e0 = offs[b * 1025 + r];
    const int e1 = offs[b * 1025 + r + 1];
    const int2* __restrict__ cs = csr + (size_t)b * 16384;
    const u32* __restrict__ supb = support + (size_t)b * 1024 * 50;

    float a0 = 0.f, a1 = 0.f;
    for (int e = e0; e < e1; ++e) {
        const int2 cv = cs[e];
        const float v = __int_as_float(cv.y);
        const u32 u = supb[(size_t)cv.x * 50 + lane];
        a0 = fmaf(v, bflo(u), a0);
        a1 = fmaf(v, bfhi(u), a1);
    }
    a0 += gcn_b[2 * lane];
    a1 += gcn_b[2 * lane + 1];
    seq[((size_t)b * 1024 + r) * 50 + lane] = packbf(a0, a1);
}

// ---------------------------------------------------------------------------
// Kernel 3: gx GEMM.  gx[m][g*50+jw] packs units (2jw,2jw+1) of gate g, bf16.
// m = b*CT + t (local to the window being computed).
// ---------------------------------------------------------------------------
__global__ __launch_bounds__(256, 2)
void gx_gemm0(const u32* __restrict__ seq, const float* __restrict__ w_ih,
              const float* __restrict__ b_ih, u32* __restrict__ gxW,
              int c0, int ctl, int CT)
{
    __shared__ float wl[10000];
    const int g    = blockIdx.x % 3;
    const int tile = blockIdx.x / 3;
    const int tid  = threadIdx.x;

    for (int i = tid; i < 10000; i += 256)
        wl[(i % 100) * 100 + (i / 100)] = w_ih[g * 10000 + i];   // transpose
    __syncthreads();

    const int m = tile * 256 + tid;              // 0 .. 128*CT-1
    const int b = m >> ctl;
    const int t = m & (CT - 1);
    const uint2* sr2 = (const uint2*)(seq + ((size_t)b * 1024 + c0 + t) * 50);

    float acc[100];
    const float4* bi4 = (const float4*)(b_ih + g * 100);
#pragma unroll
    for (int j4 = 0; j4 < 25; ++j4) {
        const float4 bv = bi4[j4];
        acc[j4*4+0] = bv.x; acc[j4*4+1] = bv.y; acc[j4*4+2] = bv.z; acc[j4*4+3] = bv.w;
    }

    for (int kk = 0; kk < 25; ++kk) {
        const uint2 up = sr2[kk];
        const float xs[4] = { bflo(up.x), bfhi(up.x), bflo(up.y), bfhi(up.y) };
#pragma unroll
        for (int q = 0; q < 4; ++q) {
            const float* wrow = &wl[(kk * 4 + q) * 100];
            const float xq = xs[q];
#pragma unroll
            for (int j4 = 0; j4 < 25; ++j4) {
                const float4 w4 = *(const float4*)(wrow + j4 * 4);
                acc[j4*4+0] = fmaf(xq, w4.x, acc[j4*4+0]);
                acc[j4*4+1] = fmaf(xq, w4.y, acc[j4*4+1]);
                acc[j4*4+2] = fmaf(xq, w4.z, acc[j4*4+2]);
                acc[j4*4+3] = fmaf(xq, w4.w, acc[j4*4+3]);
            }
        }
    }

    u32* og = gxW + (size_t)m * 150 + g * 50;
#pragma unroll
    for (int i = 0; i < 50; ++i) og[i] = packbf(acc[2*i], acc[2*i+1]);
}

// ---------------------------------------------------------------------------
// Kernel 4 (v15): GRU recurrence = v13 (verified, 568us) with the in-loop
// __syncthreads replaced by {s_waitcnt lgkmcnt(0); raw s_barrier}.
//
// ROOT CAUSE (v3-v13 invariance): hipcc emits `s_waitcnt vmcnt(0)
// lgkmcnt(0)` before every s_barrier (documented __syncthreads semantics,
// m97).  Every GRU step ends in __syncthreads while the distance-2 gx
// prefetch for t+2 is in flight -> the barrier drains it -> ~700-900 cyc of
// HBM latency exposed per step, every step.  That drain, not DS/VALU/regs,
// is why the step time sat at ~1300 cyc through ten structural rewrites
// (and why v9's extra VALU serialized AFTER the stall, and v10's extra
// waves amplified it).
//
// Fix (m201-validated pattern): raw `s_barrier` preceded by ONLY
// `s_waitcnt lgkmcnt(0)` (drains the ds_write for cross-wave LDS
// visibility; DS ops count in lgkmcnt).  The gx loads keep their
// compiler-generated COUNTED vmcnt before use -- with no forced drain they
// stay in flight across the barrier and their latency overlaps compute.
// Numerics byte-identical to v13.
// ---------------------------------------------------------------------------
__global__ __launch_bounds__(256, 1)
void gru_v15(const u32* __restrict__ gxR, size_t sampStride,
             const float* __restrict__ w_hh, const float* __restrict__ b_hh,
             float* __restrict__ hg, const float* __restrict__ fc1_w,
             const float* __restrict__ fc1_b, float* __restrict__ out,
             int first, int last, int CT)
{
    __shared__ u32 hb[2][64];           // bf16x2-packed h; [50..63] = 0

    const int tid  = threadIdx.x;
    const int samp = blockIdx.x;
    const int j    = tid >> 1;          // unit 0..127 (meaningful for j<100)
    const int p    = tid & 1;           // k-half (contiguous: p*50 .. p*50+49)
    const int hi   = j & 1;             // which bf16 half of the gx word
    const int jc   = (j < 100) ? j : 99;   // clamp so ALL loads are valid

    // ---- weights: 28 packed u32 per gate (slots s=0..27 -> m = 24p+s) -----
    // p0 real: s 0..24 ; p1 real: s 1..25 (m 25..49).  Pads = 0.
#define WDECL(g) u32 g##_0,g##_1,g##_2,g##_3,g##_4,g##_5,g##_6,g##_7,g##_8,   \
    g##_9,g##_10,g##_11,g##_12,g##_13,g##_14,g##_15,g##_16,g##_17,g##_18,     \
    g##_19,g##_20,g##_21,g##_22,g##_23,g##_24,g##_25,g##_26,g##_27
    WDECL(wr); WDECL(wz); WDECL(wn);
#undef WDECL
    {
        const float* rr = w_hh + (size_t)jc * 100;
        const float* rz = rr + 10000;
        const float* rn = rr + 20000;
#define WSLOT(s)                                                              \
        {                                                                     \
            const int  m    = 24 * p + (s);                                   \
            const int  real = p ? ((s) >= 1 && (s) <= 25) : ((s) <= 24);      \
            const int  mc   = (m < 50) ? m : 49;                              \
            float2 wv;                                                        \
            wv = *(const float2*)(rr + 2 * mc);                               \
            wr_##s = real ? packbf(wv.x, wv.y) : 0u;                          \
            wv = *(const float2*)(rz + 2 * mc);                               \
            wz_##s = real ? packbf(wv.x, wv.y) : 0u;                          \
            wv = *(const float2*)(rn + 2 * mc);                               \
            wn_##s = real ? packbf(wv.x, wv.y) : 0u;                          \
        }
        WSLOT(0)  WSLOT(1)  WSLOT(2)  WSLOT(3)  WSLOT(4)  WSLOT(5)  WSLOT(6)
        WSLOT(7)  WSLOT(8)  WSLOT(9)  WSLOT(10) WSLOT(11) WSLOT(12) WSLOT(13)
        WSLOT(14) WSLOT(15) WSLOT(16) WSLOT(17) WSLOT(18) WSLOT(19) WSLOT(20)
        WSLOT(21) WSLOT(22) WSLOT(23) WSLOT(24) WSLOT(25) WSLOT(26) WSLOT(27)
#undef WSLOT
    }

    const float bhr = b_hh[jc];
    const float bhz = b_hh[100 + jc];
    const float bhn = b_hh[200 + jc];
    float hreg = first ? 0.f : hg[samp * 100 + jc];

    // initial packed h: lane 4m packs (h_2m, h_2m+1) via DPP 0x4E exchange
    {
        u32 hb16 = f2bf1(hreg);
        u32 o16  = (u32)__builtin_amdgcn_mov_dpp((int)hb16, 0x4E, 0xF, 0xF, true);
        if (tid < 200 && (tid & 3) == 0) hb[0][tid >> 2] = hb16 | (o16 << 16);
    }
    if (tid >= 100 && tid < 114) { hb[0][tid - 50] = 0u; hb[1][tid - 50] = 0u; }
    __syncthreads();

    // gx prefetch, distance 2; clamped base so inactive threads load valid mem.
    const int w50 = ((tid >> 2) < 50) ? (tid >> 2) : 49;
    const u32* gp = gxR + (size_t)samp * sampStride + w50;
    u32 a0 = gp[0],   a1 = gp[50],  a2 = gp[100];        // t = 0
    u32 b0 = gp[150], b1 = gp[200], b2 = gp[250];        // t = 1

    int cur = 0;

    // f32 DPP reduce-add (VALU, no DS pipe)
#define DPPADD(s, CTRL)                                                       \
    (s) += __int_as_float(__builtin_amdgcn_mov_dpp(                           \
               __float_as_int(s), (CTRL), 0xF, 0xF, true))

    // acc += dot2(bf16x2 w, bf16x2 h)
#define D2(acc, w, h) asm("v_dot2_f32_bf16 %0, %1, %2, %0"                    \
                          : "+v"(acc) : "v"(w), "v"(h))

#define SG(i, s0, s1, s2, s3)                                                 \
    {                                                                         \
        const uint4 hv = hc[i];                                               \
        D2(ar0, wr_##s0, hv.x); D2(az0, wz_##s0, hv.x); D2(an0, wn_##s0, hv.x);\
        D2(ar1, wr_##s1, hv.y); D2(az1, wz_##s1, hv.y); D2(an1, wn_##s1, hv.y);\
        D2(ar0, wr_##s2, hv.z); D2(az0, wz_##s2, hv.z); D2(an0, wn_##s2, hv.z);\
        D2(ar1, wr_##s3, hv.w); D2(az1, wz_##s3, hv.w); D2(an1, wn_##s3, hv.w);\
    }

#define GRU_STEP(T, X0, X1, X2)                                               \
    {                                                                         \
        const uint4* hc = (const uint4*)(&hb[cur][24 * p]);                   \
        float ar0 = 0.f, ar1 = 0.f, az0 = 0.f, az1 = 0.f, an0 = 0.f, an1 = 0.f;\
        SG(0, 0, 1, 2, 3)   SG(1, 4, 5, 6, 7)   SG(2, 8, 9, 10, 11)           \
        SG(3, 12, 13, 14, 15) SG(4, 16, 17, 18, 19) SG(5, 20, 21, 22, 23)     \
        SG(6, 24, 25, 26, 27)                                                 \
        const u32 c0 = X0, c1 = X1, c2 = X2;                                  \
        if ((T) + 2 < CT) {                                                   \
            const u32* q2 = gp + (size_t)((T) + 2) * 150;                     \
            X0 = q2[0]; X1 = q2[50]; X2 = q2[100];                            \
        }                                                                     \
        float sr = ar0 + ar1, sz = az0 + az1, sn = an0 + an1;                 \
        DPPADD(sr, 0xB1);  DPPADD(sz, 0xB1);  DPPADD(sn, 0xB1);               \
        const float gxr = hi ? bfhi(c0) : bflo(c0);                           \
        const float gxz = hi ? bfhi(c1) : bflo(c1);                           \
        const float gxn = hi ? bfhi(c2) : bflo(c2);                           \
        const float rg  = sigm(gxr + sr + bhr);                               \
        const float zg  = sigm(gxz + sz + bhz);                               \
        const float ng  = tanh_fast(gxn + rg * (sn + bhn));                   \
        hreg = (1.f - zg) * ng + zg * hreg;                                   \
        u32 hb16 = f2bf1(hreg);                                               \
        u32 o16  = (u32)__builtin_amdgcn_mov_dpp((int)hb16, 0x4E, 0xF, 0xF,   \
                                                 true);                       \
        if (tid < 200 && (tid & 3) == 0)                                      \
            hb[cur ^ 1][tid >> 2] = hb16 | (o16 << 16);                       \
        asm volatile("s_waitcnt lgkmcnt(0)" ::: "memory");                    \
        __builtin_amdgcn_s_barrier();                                         \
        cur ^= 1;                                                             \
    }

    for (int t = 0; t < CT; t += 2) {
        GRU_STEP(t,     a0, a1, a2);
        GRU_STEP(t + 1, b0, b1, b2);
    }
#undef GRU_STEP
#undef SG
#undef D2
#undef DPPADD

    if (tid < 200 && p == 0) hg[samp * 100 + j] = hreg;

    if (last) {
        // re-stage full-precision h for the fc1 epilogue (512B LDS reused)
        float* hf = (float*)hb;
        __syncthreads();
        if (tid < 200 && p == 0) hf[j] = hreg;
        __syncthreads();
        if (tid < 100) {
            const float4* fw = (const float4*)(fc1_w + (size_t)tid * 100);
            float s0 = 0.f, s1 = 0.f, s2 = 0.f, s3 = 0.f;
#pragma unroll
            for (int kk = 0; kk < 25; ++kk) {
                const float4 wv = fw[kk];
                const float4 hv = *(const float4*)(hf + kk * 4);
                s0 = fmaf(wv.x, hv.x, s0);
                s1 = fmaf(wv.y, hv.y, s1);
                s2 = fmaf(wv.z, hv.z, s2);
                s3 = fmaf(wv.w, hv.w, s3);
            }
            const float s = (s0 + s1) + (s2 + s3) + fc1_b[tid];
            out[samp * 100 + tid] = fmaxf(s, 0.f);
        }
    }
}

// ---------------------------------------------------------------------------
extern "C" void kernel_launch(void* const* d_in, const int* in_sizes, int n_in,
                              void* d_out, int out_size, void* d_ws, size_t ws_size,
                              hipStream_t stream)
{
    const int*   neighbors = (const int*)  d_in[0];
    const int*   adj_row   = (const int*)  d_in[1];
    const int*   adj_col   = (const int*)  d_in[2];
    const float* adj_val   = (const float*)d_in[3];
    const float* emb       = (const float*)d_in[4];
    const float* gcn_w     = (const float*)d_in[5];
    const float* gcn_b     = (const float*)d_in[6];
    const float* w_ih      = (const float*)d_in[7];
    const float* w_hh      = (const float*)d_in[8];
    const float* b_ih      = (const float*)d_in[9];
    const float* b_hh      = (const float*)d_in[10];
    const float* fc1_w     = (const float*)d_in[11];
    const float* fc1_b     = (const float*)d_in[12];
    float* out = (float*)d_out;

    char* ws = (char*)d_ws;
    const size_t seq_bytes     = (size_t)128 * 1024 * 50 * 4;    // 26,214,400
    const size_t hg_bytes      = 128 * 100 * 4;                  // 51,200
    const size_t support_bytes = (size_t)128 * 1024 * 50 * 4;    // 26,214,400
    const size_t offs_bytes    = (size_t)128 * 1025 * 4;         // 524,800

    u32*   seq = (u32*)ws;
    float* hg  = (float*)(ws + seq_bytes);
    char*  rest = ws + seq_bytes + hg_bytes;
    const size_t rest_avail = ws_size - seq_bytes - hg_bytes;

    // Phase 1 (both modes): support + CSR live in `rest` (43.5 MB), all dead
    // before any gx is written over the same region.
    u32*  support = (u32*)rest;
    int*  offs    = (int*)(rest + support_bytes);
    int2* csr     = (int2*)(rest + support_bytes + offs_bytes);

    gcn_kernel<<<512, 256, 0, stream>>>(neighbors, emb, gcn_w, support);
    csr_build<<<128, 256, 0, stream>>>(adj_row, adj_col, adj_val, offs, csr);
    spmm_agg<<<dim3(205, 128), 256, 0, stream>>>(offs, csr, support, gcn_b, seq);

    const size_t gx_full = (size_t)128 * 1024 * 150 * 4;         // 78,643,200
    u32* gx = (u32*)rest;

    if (rest_avail >= gx_full) {
        // full-window: one GEMM dispatch, one 1024-step GRU dispatch
        gx_gemm0<<<1536, 256, 0, stream>>>(seq, w_ih, b_ih, gx, 0, 10, 1024);
        gru_v15<<<128, 256, 0, stream>>>(gx, (size_t)1024 * 150, w_hh, b_hh, hg,
                                         fc1_w, fc1_b, out, 1, 1, 1024);
    } else {
        // chunked fallback
        int CT = 512, ctl = 9;
        while (CT > 8 && (size_t)128 * CT * 150 * 4 > rest_avail) { CT >>= 1; --ctl; }
        const int nch = 1024 / CT;
        for (int c = 0; c < nch; ++c) {
            gx_gemm0<<<3 * (128 * CT / 256), 256, 0, stream>>>(seq, w_ih, b_ih, gx,
                                                               c * CT, ctl, CT);
            gru_v15<<<128, 256, 0, stream>>>(gx, (size_t)CT * 150, w_hh, b_hh, hg,
                                             fc1_w, fc1_b, out,
                                             (c == 0) ? 1 : 0, (c == nch - 1) ? 1 : 0, CT);
        }
    }
}

// Round 13
// 1108.049 us; speedup vs baseline: 1.0765x; 1.0765x over previous
//
#include <hip/hip_runtime.h>
#include <hip/hip_bf16.h>

// Problem constants: B=128, N=1024, E=16384, ENTITY=100000, EMB=100, HID=100

typedef unsigned int u32;
typedef float f2 __attribute__((ext_vector_type(2)));

__device__ __forceinline__ float bflo(u32 u) {
    union { u32 i; float f; } v; v.i = u << 16; return v.f;
}
__device__ __forceinline__ float bfhi(u32 u) {
    union { u32 i; float f; } v; v.i = u & 0xffff0000u; return v.f;
}
__device__ __forceinline__ u32 f2bf1(float f) {
    union { float f; u32 u; } v; v.f = f;
    return (v.u + 0x7fffu + ((v.u >> 16) & 1u)) >> 16;   // RNE
}
__device__ __forceinline__ u32 packbf(float a, float b) {
    return f2bf1(a) | (f2bf1(b) << 16);
}
__device__ __forceinline__ float sigm(float x) { return 1.f / (1.f + __expf(-x)); }
__device__ __forceinline__ float tanh_fast(float x) {
    float e = __expf(2.f * x);
    return 1.f - 2.f / (e + 1.f);
}

// ---------------------------------------------------------------------------
// Kernel 1: embedding gather + GCN matmul.  support[n][h] (bf16 packed u32)
// ---------------------------------------------------------------------------
__global__ __launch_bounds__(256, 2)
void gcn_kernel(const int* __restrict__ nb, const float* __restrict__ emb,
                const float* __restrict__ w, u32* __restrict__ support)
{
    __shared__ float wl[10000];
    for (int i = threadIdx.x; i < 10000; i += 256) wl[i] = w[i];
    __syncthreads();

    const int n = blockIdx.x * 256 + threadIdx.x;
    const long long row = nb[n];
    const float4* __restrict__ xr = (const float4*)(emb + row * 100);

    float acc[100];
#pragma unroll
    for (int h = 0; h < 100; ++h) acc[h] = 0.f;

    for (int kk = 0; kk < 25; ++kk) {
        const float4 xv = xr[kk];
        const float xs[4] = { xv.x, xv.y, xv.z, xv.w };
#pragma unroll
        for (int q = 0; q < 4; ++q) {
            const float* wrow = &wl[(kk * 4 + q) * 100];
            const float xq = xs[q];
#pragma unroll
            for (int h4 = 0; h4 < 25; ++h4) {
                const float4 w4 = *(const float4*)(wrow + h4 * 4);
                acc[h4*4+0] = fmaf(xq, w4.x, acc[h4*4+0]);
                acc[h4*4+1] = fmaf(xq, w4.y, acc[h4*4+1]);
                acc[h4*4+2] = fmaf(xq, w4.z, acc[h4*4+2]);
                acc[h4*4+3] = fmaf(xq, w4.w, acc[h4*4+3]);
            }
        }
    }

    u32* __restrict__ o = support + (size_t)n * 50;
#pragma unroll
    for (int i = 0; i < 50; ++i) o[i] = packbf(acc[2*i], acc[2*i+1]);
}

// ---------------------------------------------------------------------------
// Kernel 2a: per-sample counting-sort into CSR order.
// ---------------------------------------------------------------------------
__global__ __launch_bounds__(256, 2)
void csr_build(const int* __restrict__ arow, const int* __restrict__ acol,
               const float* __restrict__ aval,
               int* __restrict__ offs, int2* __restrict__ csr)
{
    __shared__ int cnt[1024];
    __shared__ int part[256];
    __shared__ int offl[1024];

    const int b   = blockIdx.x;
    const int tid = threadIdx.x;
    const int*   rw = arow + b * 16384;
    const int*   cl = acol + b * 16384;
    const float* vl = aval + b * 16384;

    for (int i = tid; i < 1024; i += 256) cnt[i] = 0;
    __syncthreads();
    for (int e = tid; e < 16384; e += 256) atomicAdd(&cnt[rw[e]], 1);
    __syncthreads();

    int c[4]; int s = 0;
#pragma unroll
    for (int q = 0; q < 4; ++q) { c[q] = cnt[tid * 4 + q]; s += c[q]; }
    part[tid] = s;
    __syncthreads();
    for (int off = 1; off < 256; off <<= 1) {
        int v = (tid >= off) ? part[tid - off] : 0;
        __syncthreads();
        part[tid] += v;
        __syncthreads();
    }
    int run = part[tid] - s;
#pragma unroll
    for (int q = 0; q < 4; ++q) { offl[tid * 4 + q] = run; run += c[q]; }
    __syncthreads();

    for (int i = tid; i < 1024; i += 256) offs[b * 1025 + i] = offl[i];
    if (tid == 0) offs[b * 1025 + 1024] = 16384;

    int2* cs = csr + (size_t)b * 16384;
    for (int e = tid; e < 16384; e += 256) {
        const int r   = rw[e];
        const int pos = atomicAdd(&offl[r], 1);
        int2 cv; cv.x = cl[e]; cv.y = __float_as_int(vl[e]);
        cs[pos] = cv;
    }
}

// ---------------------------------------------------------------------------
// Kernel 2b: atomic-free CSR aggregate.  50 lanes/row.
// v16: 4-deep software pipeline on the edge loop.  The old loop was a serial
// dependent-load chain (cs[e] ~200cyc L2 -> supb gather ~250-400cyc -> fma),
// ~16 deep per row, with only ~2 waves/SIMD of TLP (round-0: VALUBusy 5.6%,
// Occupancy 25% -> latency-bound).  4-way unroll issues 4 cv loads together,
// then 4 gathers together -> ~4x memory-level parallelism per wave.
// FMA accumulation order unchanged -> bit-identical numerics.
// ---------------------------------------------------------------------------
__global__ __launch_bounds__(256, 4)
void spmm_agg(const int* __restrict__ offs, const int2* __restrict__ csr,
              const u32* __restrict__ support,
              const float* __restrict__ gcn_b, u32* __restrict__ seq)
{
    const int b    = blockIdx.y;
    const int lr   = threadIdx.x / 50;
    const int lane = threadIdx.x % 50;
    const int r    = blockIdx.x * 5 + lr;
    if (lr >= 5 || r >= 1024) return;

    const int e0 = offs[b * 1025 + r];
    const int e1 = offs[b * 1025 + r + 1];
    const int2* __restrict__ cs = csr + (size_t)b * 16384;
    const u32* __restrict__ supb = support + (size_t)b * 1024 * 50;

    float a0 = 0.f, a1 = 0.f;
    int e = e0;
    const int e4 = e0 + ((e1 - e0) & ~3);
    for (; e < e4; e += 4) {
        const int2 c0 = cs[e];
        const int2 c1 = cs[e + 1];
        const int2 c2 = cs[e + 2];
        const int2 c3 = cs[e + 3];
        const u32 u0 = supb[(size_t)c0.x * 50 + lane];
        const u32 u1 = supb[(size_t)c1.x * 50 + lane];
        const u32 u2 = supb[(size_t)c2.x * 50 + lane];
        const u32 u3 = supb[(size_t)c3.x * 50 + lane];
        const float v0 = __int_as_float(c0.y);
        const float v1 = __int_as_float(c1.y);
        const float v2 = __int_as_float(c2.y);
        const float v3 = __int_as_float(c3.y);
        a0 = fmaf(v0, bflo(u0), a0);  a1 = fmaf(v0, bfhi(u0), a1);
        a0 = fmaf(v1, bflo(u1), a0);  a1 = fmaf(v1, bfhi(u1), a1);
        a0 = fmaf(v2, bflo(u2), a0);  a1 = fmaf(v2, bfhi(u2), a1);
        a0 = fmaf(v3, bflo(u3), a0);  a1 = fmaf(v3, bfhi(u3), a1);
    }
    for (; e < e1; ++e) {
        const int2 cv = cs[e];
        const float v = __int_as_float(cv.y);
        const u32 u = supb[(size_t)cv.x * 50 + lane];
        a0 = fmaf(v, bflo(u), a0);
        a1 = fmaf(v, bfhi(u), a1);
    }
    a0 += gcn_b[2 * lane];
    a1 += gcn_b[2 * lane + 1];
    seq[((size_t)b * 1024 + r) * 50 + lane] = packbf(a0, a1);
}

// ---------------------------------------------------------------------------
// Kernel 3: gx GEMM.  gx[m][g*50+jw] packs units (2jw,2jw+1) of gate g, bf16.
// m = b*CT + t (local to the window being computed).
// ---------------------------------------------------------------------------
__global__ __launch_bounds__(256, 2)
void gx_gemm0(const u32* __restrict__ seq, const float* __restrict__ w_ih,
              const float* __restrict__ b_ih, u32* __restrict__ gxW,
              int c0, int ctl, int CT)
{
    __shared__ float wl[10000];
    const int g    = blockIdx.x % 3;
    const int tile = blockIdx.x / 3;
    const int tid  = threadIdx.x;

    for (int i = tid; i < 10000; i += 256)
        wl[(i % 100) * 100 + (i / 100)] = w_ih[g * 10000 + i];   // transpose
    __syncthreads();

    const int m = tile * 256 + tid;              // 0 .. 128*CT-1
    const int b = m >> ctl;
    const int t = m & (CT - 1);
    const uint2* sr2 = (const uint2*)(seq + ((size_t)b * 1024 + c0 + t) * 50);

    float acc[100];
    const float4* bi4 = (const float4*)(b_ih + g * 100);
#pragma unroll
    for (int j4 = 0; j4 < 25; ++j4) {
        const float4 bv = bi4[j4];
        acc[j4*4+0] = bv.x; acc[j4*4+1] = bv.y; acc[j4*4+2] = bv.z; acc[j4*4+3] = bv.w;
    }

    for (int kk = 0; kk < 25; ++kk) {
        const uint2 up = sr2[kk];
        const float xs[4] = { bflo(up.x), bfhi(up.x), bflo(up.y), bfhi(up.y) };
#pragma unroll
        for (int q = 0; q < 4; ++q) {
            const float* wrow = &wl[(kk * 4 + q) * 100];
            const float xq = xs[q];
#pragma unroll
            for (int j4 = 0; j4 < 25; ++j4) {
                const float4 w4 = *(const float4*)(wrow + j4 * 4);
                acc[j4*4+0] = fmaf(xq, w4.x, acc[j4*4+0]);
                acc[j4*4+1] = fmaf(xq, w4.y, acc[j4*4+1]);
                acc[j4*4+2] = fmaf(xq, w4.z, acc[j4*4+2]);
                acc[j4*4+3] = fmaf(xq, w4.w, acc[j4*4+3]);
            }
        }
    }

    u32* og = gxW + (size_t)m * 150 + g * 50;
#pragma unroll
    for (int i = 0; i < 50; ++i) og[i] = packbf(acc[2*i], acc[2*i+1]);
}

// ---------------------------------------------------------------------------
// Kernel 4 (v15, FROZEN at 566us): GRU recurrence, 1 sample/block, 256
// threads (4 waves).  bf16-packed h in LDS (7 b128 reads/thread), DPP
// combine, v_dot2_f32_bf16, bf16-packed weights in 84 named u32, one
// raw-barrier/step, distance-2 gx prefetch.  13 rounds of evidence: the
// ~1327 cyc/step is a fixed serial latency chain (LDS round trip + dot
// chains + 2 dependent transcendental chains + barrier) invariant to DS
// count, registers, VALU mix, and barrier semantics.
// ---------------------------------------------------------------------------
__global__ __launch_bounds__(256, 1)
void gru_v15(const u32* __restrict__ gxR, size_t sampStride,
             const float* __restrict__ w_hh, const float* __restrict__ b_hh,
             float* __restrict__ hg, const float* __restrict__ fc1_w,
             const float* __restrict__ fc1_b, float* __restrict__ out,
             int first, int last, int CT)
{
    __shared__ u32 hb[2][64];           // bf16x2-packed h; [50..63] = 0

    const int tid  = threadIdx.x;
    const int samp = blockIdx.x;
    const int j    = tid >> 1;          // unit 0..127 (meaningful for j<100)
    const int p    = tid & 1;           // k-half (contiguous: p*50 .. p*50+49)
    const int hi   = j & 1;             // which bf16 half of the gx word
    const int jc   = (j < 100) ? j : 99;   // clamp so ALL loads are valid

    // ---- weights: 28 packed u32 per gate (slots s=0..27 -> m = 24p+s) -----
    // p0 real: s 0..24 ; p1 real: s 1..25 (m 25..49).  Pads = 0.
#define WDECL(g) u32 g##_0,g##_1,g##_2,g##_3,g##_4,g##_5,g##_6,g##_7,g##_8,   \
    g##_9,g##_10,g##_11,g##_12,g##_13,g##_14,g##_15,g##_16,g##_17,g##_18,     \
    g##_19,g##_20,g##_21,g##_22,g##_23,g##_24,g##_25,g##_26,g##_27
    WDECL(wr); WDECL(wz); WDECL(wn);
#undef WDECL
    {
        const float* rr = w_hh + (size_t)jc * 100;
        const float* rz = rr + 10000;
        const float* rn = rr + 20000;
#define WSLOT(s)                                                              \
        {                                                                     \
            const int  m    = 24 * p + (s);                                   \
            const int  real = p ? ((s) >= 1 && (s) <= 25) : ((s) <= 24);      \
            const int  mc   = (m < 50) ? m : 49;                              \
            float2 wv;                                                        \
            wv = *(const float2*)(rr + 2 * mc);                               \
            wr_##s = real ? packbf(wv.x, wv.y) : 0u;                          \
            wv = *(const float2*)(rz + 2 * mc);                               \
            wz_##s = real ? packbf(wv.x, wv.y) : 0u;                          \
            wv = *(const float2*)(rn + 2 * mc);                               \
            wn_##s = real ? packbf(wv.x, wv.y) : 0u;                          \
        }
        WSLOT(0)  WSLOT(1)  WSLOT(2)  WSLOT(3)  WSLOT(4)  WSLOT(5)  WSLOT(6)
        WSLOT(7)  WSLOT(8)  WSLOT(9)  WSLOT(10) WSLOT(11) WSLOT(12) WSLOT(13)
        WSLOT(14) WSLOT(15) WSLOT(16) WSLOT(17) WSLOT(18) WSLOT(19) WSLOT(20)
        WSLOT(21) WSLOT(22) WSLOT(23) WSLOT(24) WSLOT(25) WSLOT(26) WSLOT(27)
#undef WSLOT
    }

    const float bhr = b_hh[jc];
    const float bhz = b_hh[100 + jc];
    const float bhn = b_hh[200 + jc];
    float hreg = first ? 0.f : hg[samp * 100 + jc];

    // initial packed h: lane 4m packs (h_2m, h_2m+1) via DPP 0x4E exchange
    {
        u32 hb16 = f2bf1(hreg);
        u32 o16  = (u32)__builtin_amdgcn_mov_dpp((int)hb16, 0x4E, 0xF, 0xF, true);
        if (tid < 200 && (tid & 3) == 0) hb[0][tid >> 2] = hb16 | (o16 << 16);
    }
    if (tid >= 100 && tid < 114) { hb[0][tid - 50] = 0u; hb[1][tid - 50] = 0u; }
    __syncthreads();

    // gx prefetch, distance 2; clamped base so inactive threads load valid mem.
    const int w50 = ((tid >> 2) < 50) ? (tid >> 2) : 49;
    const u32* gp = gxR + (size_t)samp * sampStride + w50;
    u32 a0 = gp[0],   a1 = gp[50],  a2 = gp[100];        // t = 0
    u32 b0 = gp[150], b1 = gp[200], b2 = gp[250];        // t = 1

    int cur = 0;

    // f32 DPP reduce-add (VALU, no DS pipe)
#define DPPADD(s, CTRL)                                                       \
    (s) += __int_as_float(__builtin_amdgcn_mov_dpp(                           \
               __float_as_int(s), (CTRL), 0xF, 0xF, true))

    // acc += dot2(bf16x2 w, bf16x2 h)
#define D2(acc, w, h) asm("v_dot2_f32_bf16 %0, %1, %2, %0"                    \
                          : "+v"(acc) : "v"(w), "v"(h))

#define SG(i, s0, s1, s2, s3)                                                 \
    {                                                                         \
        const uint4 hv = hc[i];                                               \
        D2(ar0, wr_##s0, hv.x); D2(az0, wz_##s0, hv.x); D2(an0, wn_##s0, hv.x);\
        D2(ar1, wr_##s1, hv.y); D2(az1, wz_##s1, hv.y); D2(an1, wn_##s1, hv.y);\
        D2(ar0, wr_##s2, hv.z); D2(az0, wz_##s2, hv.z); D2(an0, wn_##s2, hv.z);\
        D2(ar1, wr_##s3, hv.w); D2(az1, wz_##s3, hv.w); D2(an1, wn_##s3, hv.w);\
    }

#define GRU_STEP(T, X0, X1, X2)                                               \
    {                                                                         \
        const uint4* hc = (const uint4*)(&hb[cur][24 * p]);                   \
        float ar0 = 0.f, ar1 = 0.f, az0 = 0.f, az1 = 0.f, an0 = 0.f, an1 = 0.f;\
        SG(0, 0, 1, 2, 3)   SG(1, 4, 5, 6, 7)   SG(2, 8, 9, 10, 11)           \
        SG(3, 12, 13, 14, 15) SG(4, 16, 17, 18, 19) SG(5, 20, 21, 22, 23)     \
        SG(6, 24, 25, 26, 27)                                                 \
        const u32 c0 = X0, c1 = X1, c2 = X2;                                  \
        if ((T) + 2 < CT) {                                                   \
            const u32* q2 = gp + (size_t)((T) + 2) * 150;                     \
            X0 = q2[0]; X1 = q2[50]; X2 = q2[100];                            \
        }                                                                     \
        float sr = ar0 + ar1, sz = az0 + az1, sn = an0 + an1;                 \
        DPPADD(sr, 0xB1);  DPPADD(sz, 0xB1);  DPPADD(sn, 0xB1);               \
        const float gxr = hi ? bfhi(c0) : bflo(c0);                           \
        const float gxz = hi ? bfhi(c1) : bflo(c1);                           \
        const float gxn = hi ? bfhi(c2) : bflo(c2);                           \
        const float rg  = sigm(gxr + sr + bhr);                               \
        const float zg  = sigm(gxz + sz + bhz);                               \
        const float ng  = tanh_fast(gxn + rg * (sn + bhn));                   \
        hreg = (1.f - zg) * ng + zg * hreg;                                   \
        u32 hb16 = f2bf1(hreg);                                               \
        u32 o16  = (u32)__builtin_amdgcn_mov_dpp((int)hb16, 0x4E, 0xF, 0xF,   \
                                                 true);                       \
        if (tid < 200 && (tid & 3) == 0)                                      \
            hb[cur ^ 1][tid >> 2] = hb16 | (o16 << 16);                       \
        asm volatile("s_waitcnt lgkmcnt(0)" ::: "memory");                    \
        __builtin_amdgcn_s_barrier();                                         \
        cur ^= 1;                                                             \
    }

    for (int t = 0; t < CT; t += 2) {
        GRU_STEP(t,     a0, a1, a2);
        GRU_STEP(t + 1, b0, b1, b2);
    }
#undef GRU_STEP
#undef SG
#undef D2
#undef DPPADD

    if (tid < 200 && p == 0) hg[samp * 100 + j] = hreg;

    if (last) {
        // re-stage full-precision h for the fc1 epilogue (512B LDS reused)
        float* hf = (float*)hb;
        __syncthreads();
        if (tid < 200 && p == 0) hf[j] = hreg;
        __syncthreads();
        if (tid < 100) {
            const float4* fw = (const float4*)(fc1_w + (size_t)tid * 100);
            float s0 = 0.f, s1 = 0.f, s2 = 0.f, s3 = 0.f;
#pragma unroll
            for (int kk = 0; kk < 25; ++kk) {
                const float4 wv = fw[kk];
                const float4 hv = *(const float4*)(hf + kk * 4);
                s0 = fmaf(wv.x, hv.x, s0);
                s1 = fmaf(wv.y, hv.y, s1);
                s2 = fmaf(wv.z, hv.z, s2);
                s3 = fmaf(wv.w, hv.w, s3);
            }
            const float s = (s0 + s1) + (s2 + s3) + fc1_b[tid];
            out[samp * 100 + tid] = fmaxf(s, 0.f);
        }
    }
}

// ---------------------------------------------------------------------------
extern "C" void kernel_launch(void* const* d_in, const int* in_sizes, int n_in,
                              void* d_out, int out_size, void* d_ws, size_t ws_size,
                              hipStream_t stream)
{
    const int*   neighbors = (const int*)  d_in[0];
    const int*   adj_row   = (const int*)  d_in[1];
    const int*   adj_col   = (const int*)  d_in[2];
    const float* adj_val   = (const float*)d_in[3];
    const float* emb       = (const float*)d_in[4];
    const float* gcn_w     = (const float*)d_in[5];
    const float* gcn_b     = (const float*)d_in[6];
    const float* w_ih      = (const float*)d_in[7];
    const float* w_hh      = (const float*)d_in[8];
    const float* b_ih      = (const float*)d_in[9];
    const float* b_hh      = (const float*)d_in[10];
    const float* fc1_w     = (const float*)d_in[11];
    const float* fc1_b     = (const float*)d_in[12];
    float* out = (float*)d_out;

    char* ws = (char*)d_ws;
    const size_t seq_bytes     = (size_t)128 * 1024 * 50 * 4;    // 26,214,400
    const size_t hg_bytes      = 128 * 100 * 4;                  // 51,200
    const size_t support_bytes = (size_t)128 * 1024 * 50 * 4;    // 26,214,400
    const size_t offs_bytes    = (size_t)128 * 1025 * 4;         // 524,800

    u32*   seq = (u32*)ws;
    float* hg  = (float*)(ws + seq_bytes);
    char*  rest = ws + seq_bytes + hg_bytes;
    const size_t rest_avail = ws_size - seq_bytes - hg_bytes;

    // Phase 1 (both modes): support + CSR live in `rest` (43.5 MB), all dead
    // before any gx is written over the same region.
    u32*  support = (u32*)rest;
    int*  offs    = (int*)(rest + support_bytes);
    int2* csr     = (int2*)(rest + support_bytes + offs_bytes);

    gcn_kernel<<<512, 256, 0, stream>>>(neighbors, emb, gcn_w, support);
    csr_build<<<128, 256, 0, stream>>>(adj_row, adj_col, adj_val, offs, csr);
    spmm_agg<<<dim3(205, 128), 256, 0, stream>>>(offs, csr, support, gcn_b, seq);

    const size_t gx_full = (size_t)128 * 1024 * 150 * 4;         // 78,643,200
    u32* gx = (u32*)rest;

    if (rest_avail >= gx_full) {
        // full-window: one GEMM dispatch, one 1024-step GRU dispatch
        gx_gemm0<<<1536, 256, 0, stream>>>(seq, w_ih, b_ih, gx, 0, 10, 1024);
        gru_v15<<<128, 256, 0, stream>>>(gx, (size_t)1024 * 150, w_hh, b_hh, hg,
                                         fc1_w, fc1_b, out, 1, 1, 1024);
    } else {
        // chunked fallback
        int CT = 512, ctl = 9;
        while (CT > 8 && (size_t)128 * CT * 150 * 4 > rest_avail) { CT >>= 1; --ctl; }
        const int nch = 1024 / CT;
        for (int c = 0; c < nch; ++c) {
            gx_gemm0<<<3 * (128 * CT / 256), 256, 0, stream>>>(seq, w_ih, b_ih, gx,
                                                               c * CT, ctl, CT);
            gru_v15<<<128, 256, 0, stream>>>(gx, (size_t)CT * 150, w_hh, b_hh, hg,
                                             fc1_w, fc1_b, out,
                                             (c == 0) ? 1 : 0, (c == nch - 1) ? 1 : 0, CT);
        }
    }
}